// Round 8
// baseline (248.188 us; speedup 1.0000x reference)
//
#include <hip/hip_runtime.h>
#include <math.h>

#define T_TOKENS 16384
#define HDIM     2048
#define NEXP     128
#define TOPK     8

#define BK    64                 // k per chunk (2 MFMA k-steps)
#define NCH   (HDIM / BK)        // 32 chunks
#define TM    32                 // tokens per block

#define F16_MIN_NORM    6.1035156e-05f
#define SPLIT_SCALE     4096.0f
#define INV_SPLIT_SCALE 2.44140625e-04f   // 2^-12

typedef __attribute__((ext_vector_type(8))) _Float16 f16x8;  // A/B frag: 4 VGPR
typedef __attribute__((ext_vector_type(4))) float    f32x4;  // C/D frag + loads

#define LGKM0()   asm volatile("s_waitcnt lgkmcnt(0)" ::: "memory")

// x = hi + lo*2^-12 (f16 RNE each); residual <= 2^-24|x|. Numerics verified R3-R8.
__device__ __forceinline__ void f16split(float f, _Float16& hi, _Float16& lo) {
    _Float16 h = (_Float16)f;
    float back = (float)h;
    if (fabsf(f) < F16_MIN_NORM) { h = (_Float16)0.f; back = 0.f; }
    lo = (_Float16)((f - back) * SPLIT_SCALE);
    hi = h;
}

// A-plane LDS swizzle (within-plane BYTE offset, plane = 4096 B).
// Write byte = q*2048 + sr4*1024 + c*256 + s15*16 (granule was s15&7 only ->
// 4x quarter-wave conflict, the 7.34M counter). Mix c (bits 8:9) and q (bit 11)
// into the bank-quad bits: granule' = s^c^4q -> each granule 2x per 16-lane
// quarter on BOTH write and read (read granule' = (col&7)^quad^4kk). Bijective.
__device__ __forceinline__ int swz(int b) {
    return b ^ (((b >> 8) & 3) << 4) ^ (((b >> 11) & 1) << 6);
}

// ---- prep: split w AND repack into MFMA B-frag order (verified, unchanged) ----
// packed[s]: ((kk*8 + nt)*64 + lane) * 8 f16; kk = global 32-k step, nt = expert/16.
__global__ __launch_bounds__(256) void pack_w(const float* __restrict__ w,
                                              unsigned short* __restrict__ wp1,
                                              unsigned short* __restrict__ wp2) {
    int p = blockIdx.x * 256 + threadIdx.x;       // 0 .. 64*8*64-1
    int lane = p & 63, nt = (p >> 6) & 7, kk = p >> 9;
    int col = lane & 15, quad = lane >> 4;
    const float* src = w + (size_t)(nt * 16 + col) * HDIM + kk * 32 + quad * 8;
    unsigned short h[8], l[8];
#pragma unroll
    for (int j = 0; j < 8; ++j) {
        _Float16 hh, ll;
        f16split(src[j], hh, ll);
        union { _Float16 x; unsigned short u; } ch, cl;
        ch.x = hh; cl.x = ll;
        h[j] = ch.u; l[j] = cl.u;
    }
    *(uint4*)(wp1 + (size_t)p * 8) = *(const uint4*)h;
    *(uint4*)(wp2 + (size_t)p * 8) = *(const uint4*)l;
}

struct BRegs { f16x8 v[8]; };    // [(kk*2+j)*2+plane] — static indexing only

// ---- fused gate v9: swizzled shared-A LDS + direct-reg B + 2 blocks/CU ----
// R0/R7 (shared-A) = 108-115us beat all per-wave-A variants (140-150) => A-sharing
// is load-bearing. Remaining longest pole = LDS pipe: A-store conflicts (~900cy/chunk,
// the 7.34M counter) + B's LDS round-trip (~1000cy/chunk) which launders data with
// ZERO inter-wave reuse. v9: (1) XOR-swizzle A planes both sides -> conflict-free;
// (2) B per-wave direct global->reg (lane-contiguous 16B/lane from L2-hot wp, frag
// layout = memory layout), ping-pong, issued 1 iter ahead AFTER its consumer MFMA;
// FIFO: B waits subsumed by older A waits. (3) TM=32/256thr/grid512 -> 2 blocks/CU,
// two independent barrier domains overlap each other's stalls. 1 raw barrier/chunk
// (publishes A buf only; nothing else needs sync).
__global__ __launch_bounds__(256, 2) void moe_gate(const float* __restrict__ x,
                                                   const unsigned short* __restrict__ wp1,
                                                   const unsigned short* __restrict__ wp2,
                                                   float* __restrict__ out_idx,
                                                   float* __restrict__ out_w) {
    // [buf0: A1 0..4K, A2 4K..8K][buf1: A1 8K..12K, A2 12K..16K]; epil overlays all
    __shared__ __align__(16) unsigned char smem[17408];
    float* epil = (float*)smem;                    // [32][132] f32 = 16.9 KB union

    const int tid  = threadIdx.x;
    const int lane = tid & 63;
    const int wv   = tid >> 6;        // expert group 0..3 (nt = wv*2 + j)
    const int col  = lane & 15;       // A: token-in-tile, B: expert-in-tile, D: col
    const int quad = lane >> 4;       // A/B: k-seg, D: row group
    const long tok0 = (long)blockIdx.x * TM;

    // A staging: thread t -> srow = t>>3 (0..31), kseg = t&7 -> 8 f32 at k=kseg*8.
    // 8 threads cover one 256B row-chunk (coalesced). Dest cell (verified R0 map):
    const int srow = tid >> 3, skseg = tid & 7;
    const float* xgs = x + (tok0 + srow) * (long)HDIM + skseg * 8;
    const int acell = (((skseg >> 2) * 2 + (srow >> 4)) * 64 + (skseg & 3) * 16 + (srow & 15));
    const int adst  = swz(acell * 16);             // swizzled byte offset within plane

    f32x4 acc[2][2], accc[2][2];      // [m][j] main + cross (static-indexed)
#pragma unroll
    for (int m = 0; m < 2; ++m)
#pragma unroll
        for (int j = 0; j < 2; ++j) { acc[m][j] = (f32x4){0,0,0,0}; accc[m][j] = (f32x4){0,0,0,0}; }

    f32x4 Av0, Av1;                   // this thread's 8 staged f32 (1-chunk prefetch)

    auto loadA = [&](int ch) {        // 2 coalesced 16B loads
        Av0 = *(const f32x4*)(xgs + ch * BK);
        Av1 = *(const f32x4*)(xgs + ch * BK + 4);
    };
    auto splitWriteA = [&](int b) {   // 8 f16splits -> one uint4 per plane, swizzled
        unsigned short h[8], l[8];
#pragma unroll
        for (int j = 0; j < 8; ++j) {
            _Float16 hh, ll;
            f16split(j < 4 ? Av0[j] : Av1[j - 4], hh, ll);
            union { _Float16 x; unsigned short u; } ch_, cl_;
            ch_.x = hh; cl_.x = ll;
            h[j] = ch_.u; l[j] = cl_.u;
        }
        unsigned char* base = smem + b * 8192;
        *(uint4*)(base + adst)        = *(const uint4*)h;
        *(uint4*)(base + 4096 + adst) = *(const uint4*)l;
    };
    auto loadB = [&](int ch, BRegs& B) {   // 8 lane-contiguous 16B loads (1KB/instr, L2)
        const size_t cho = (size_t)ch * 8192;
#pragma unroll
        for (int kk = 0; kk < 2; ++kk)
#pragma unroll
            for (int j = 0; j < 2; ++j) {
                const size_t o = cho + (size_t)(((kk * 8) + (wv * 2 + j)) * 64 + lane) * 8;
                B.v[(kk * 2 + j) * 2 + 0] = *(const f16x8*)(wp1 + o);
                B.v[(kk * 2 + j) * 2 + 1] = *(const f16x8*)(wp2 + o);
            }
    };
    auto mfmaStep = [&](int b, BRegs& B) { // 8 swizzled conflict-free ds_read_b128 + 24 MFMA
        const unsigned char* base = smem + b * 8192;
#pragma unroll
        for (int kk = 0; kk < 2; ++kk) {
            f16x8 af1v[2], af2v[2];
#pragma unroll
            for (int m = 0; m < 2; ++m) {
                const int bo = swz(((kk * 2 + m) * 64 + lane) * 16);
                af1v[m] = *(const f16x8*)(base + bo);
                af2v[m] = *(const f16x8*)(base + 4096 + bo);
            }
#pragma unroll
            for (int j = 0; j < 2; ++j) {
                f16x8 bf1 = B.v[(kk * 2 + j) * 2 + 0];
                f16x8 bf2 = B.v[(kk * 2 + j) * 2 + 1];
#pragma unroll
                for (int m = 0; m < 2; ++m) {
                    acc[m][j]  = __builtin_amdgcn_mfma_f32_16x16x32_f16(af1v[m], bf1, acc[m][j],  0, 0, 0);
                    accc[m][j] = __builtin_amdgcn_mfma_f32_16x16x32_f16(af1v[m], bf2, accc[m][j], 0, 0, 0);
                    accc[m][j] = __builtin_amdgcn_mfma_f32_16x16x32_f16(af2v[m], bf1, accc[m][j], 0, 0, 0);
                }
            }
        }
    };

    BRegs B0, B1;                     // ping-pong: B(even)->B0, B(odd)->B1, 1 iter ahead

    // ---- prologue ----
    loadA(0);
    loadB(0, B0);
    loadB(1, B1);
    splitWriteA(0);                   // waits A(0) (drains prologue B too; one-time)
    loadA(1);
    LGKM0();
    __builtin_amdgcn_s_barrier();     // publish buf0

    // steady: 1 barrier/chunk; per even half (odd symmetric):
    //   splitA(ch+1)->buf1 [waits A(ch+1), issued 1 chunk ago]
    //   loadA(ch+2) | mfma(buf0, B0=B(ch)) [B wait subsumed] | loadB(ch+2)->B0 (WAR-safe)
    for (int ch = 0; ch < NCH - 2; ch += 2) {
        splitWriteA(1);
        loadA(ch + 2);
        mfmaStep(0, B0);
        loadB(ch + 2, B0);
        LGKM0();
        __builtin_amdgcn_s_barrier();

        splitWriteA(0);
        loadA(ch + 3);
        mfmaStep(1, B1);
        loadB(ch + 3, B1);
        LGKM0();
        __builtin_amdgcn_s_barrier();
    }
    // tail: ch = NCH-2, NCH-1
    splitWriteA(1);                   // A(NCH-1) -> buf1 (loaded in last odd half)
    mfmaStep(0, B0);                  // chunk NCH-2
    LGKM0();
    __builtin_amdgcn_s_barrier();
    mfmaStep(1, B1);                  // chunk NCH-1
    __syncthreads();                  // all LDS reads done before epil overlay

    // ---- epilogue: logits -> LDS; D layout: token = m*16+quad*4+r, expert = (wv*2+j)*16+col
#pragma unroll
    for (int m = 0; m < 2; ++m)
#pragma unroll
        for (int j = 0; j < 2; ++j)
#pragma unroll
            for (int r = 0; r < 4; ++r)
                epil[(m * 16 + quad * 4 + r) * 132 + (wv * 2 + j) * 16 + col] =
                    acc[m][j][r] + accc[m][j][r] * INV_SPLIT_SCALE;
    __syncthreads();

    // ---- top-8 + renorm softmax: 8 tokens per wave (butterfly, verified) ----
    for (int i = 0; i < 8; ++i) {
        const int t = wv * 8 + i;
        float2 p = *(const float2*)(epil + t * 132 + 2 * lane);
        float v0 = p.x, v1 = p.y;
        const int i0 = 2 * lane, i1 = 2 * lane + 1;

        float topv[TOPK];
        int topi[TOPK];
#pragma unroll
        for (int s = 0; s < TOPK; ++s) {
            float mv = (v0 >= v1) ? v0 : v1;          // tie -> smaller index
            int   mi = (v0 >= v1) ? i0 : i1;
#pragma unroll
            for (int off = 32; off >= 1; off >>= 1) {
                float ov = __shfl_xor(mv, off);
                int   oi = __shfl_xor(mi, off);
                if (ov > mv || (ov == mv && oi < mi)) { mv = ov; mi = oi; }
            }
            topv[s] = mv; topi[s] = mi;
            if (i0 == mi) v0 = -INFINITY;
            if (i1 == mi) v1 = -INFINITY;
        }

        const float m = topv[0];
        float sum = 0.f;
#pragma unroll
        for (int s = 0; s < TOPK; ++s) sum += expf(topv[s] - m);
        const float inv = 1.f / sum;

        float myv = topv[0]; int myi = topi[0];
#pragma unroll
        for (int s = 1; s < TOPK; ++s)
            if (lane == s) { myv = topv[s]; myi = topi[s]; }

        if (lane < TOPK) {
            long tok = tok0 + t;
            out_idx[tok * TOPK + lane] = (float)myi;
            out_w[tok * TOPK + lane]   = expf(myv - m) * inv;
        }
    }
}

extern "C" void kernel_launch(void* const* d_in, const int* in_sizes, int n_in,
                              void* d_out, int out_size, void* d_ws, size_t ws_size,
                              hipStream_t stream) {
    const float* x = (const float*)d_in[0];   // [4,4096,2048] fp32
    const float* w = (const float*)d_in[1];   // [128,2048] fp32
    float* out = (float*)d_out;               // [T*8 idx][T*8 weights] flat fp32

    unsigned short* wp1 = (unsigned short*)d_ws;           // 512 KB packed hi
    unsigned short* wp2 = wp1 + (size_t)NEXP * HDIM;       // 512 KB packed lo

    pack_w<<<(64 * 8 * 64) / 256, 256, 0, stream>>>(w, wp1, wp2);
    moe_gate<<<T_TOKENS / TM, 256, 0, stream>>>(x, wp1, wp2, out, out + (size_t)T_TOKENS * TOPK);
}

// Round 9
// 234.340 us; speedup vs baseline: 1.0591x; 1.0591x over previous
//
#include <hip/hip_runtime.h>
#include <math.h>

#define T_TOKENS 16384
#define HDIM     2048
#define NEXP     128
#define TOPK     8

#define BK    128                // k per chunk (4 MFMA k-steps)  [v10: was 64]
#define NCH   (HDIM / BK)        // 16 chunks
#define TM    32                 // tokens per block

#define F16_MIN_NORM    6.1035156e-05f
#define SPLIT_SCALE     4096.0f
#define INV_SPLIT_SCALE 2.44140625e-04f   // 2^-12

typedef __attribute__((ext_vector_type(8))) _Float16 f16x8;  // A/B frag: 4 VGPR
typedef __attribute__((ext_vector_type(4))) float    f32x4;  // C/D frag + loads

#define LGKM0()   asm volatile("s_waitcnt lgkmcnt(0)" ::: "memory")

// x = hi + lo*2^-12 (f16 RNE each); residual <= 2^-24|x|. Numerics verified R3-R8.
__device__ __forceinline__ void f16split(float f, _Float16& hi, _Float16& lo) {
    _Float16 h = (_Float16)f;
    float back = (float)h;
    if (fabsf(f) < F16_MIN_NORM) { h = (_Float16)0.f; back = 0.f; }
    lo = (_Float16)((f - back) * SPLIT_SCALE);
    hi = h;
}

// A-plane LDS swizzle (within-plane BYTE offset, plane = 8192 B for BK=128).
// Write byte = g*1024 + (s&3)*256 + (srow&15)*16, g = (s>>2)*2 + (srow>>4).
// Unswizzled write granule = srow&7 -> 8-way/quarter. Mix byte bits 8,9 (=s&3)
// and 11 (=(s>>2)&1) into granule bits: write granule' = (srow&7)^(s&7) -> 2-way
// (free); read granule' = (lane&7)^const-per-quarter -> 2-way (free). Bijective.
// Same formula as R9 (verified 0 conflicts on HW); re-derived for BK=128 layout.
__device__ __forceinline__ int swz(int b) {
    return b ^ (((b >> 8) & 3) << 4) ^ (((b >> 11) & 1) << 6);
}

// ---- prep: split w AND repack into MFMA B-frag order (verified, unchanged) ----
// packed[s]: ((kkg*8 + nt)*64 + lane) * 8 f16; kkg = global 32-k step, nt = expert/16.
__global__ __launch_bounds__(256) void pack_w(const float* __restrict__ w,
                                              unsigned short* __restrict__ wp1,
                                              unsigned short* __restrict__ wp2) {
    int p = blockIdx.x * 256 + threadIdx.x;       // 0 .. 64*8*64-1
    int lane = p & 63, nt = (p >> 6) & 7, kk = p >> 9;
    int col = lane & 15, quad = lane >> 4;
    const float* src = w + (size_t)(nt * 16 + col) * HDIM + kk * 32 + quad * 8;
    unsigned short h[8], l[8];
#pragma unroll
    for (int j = 0; j < 8; ++j) {
        _Float16 hh, ll;
        f16split(src[j], hh, ll);
        union { _Float16 x; unsigned short u; } ch, cl;
        ch.x = hh; cl.x = ll;
        h[j] = ch.u; l[j] = cl.u;
    }
    *(uint4*)(wp1 + (size_t)p * 8) = *(const uint4*)h;
    *(uint4*)(wp2 + (size_t)p * 8) = *(const uint4*)l;
}

struct ARegs { f32x4 v[4]; };     // 16 f32: ksegs {skseg, skseg+8} x 8 — static idx
struct BRegs { f16x8 v[16]; };    // [kk(4)][j(2)][plane(2)] — static idx

// ---- fused gate v10: R8 structure with BK=128 (16 serial chunks, was 32) ----
// Nine rounds of evidence: shared-A is load-bearing (+30%); barrier count, B-path,
// conflicts, vmcnt discipline all ±3%. The untested axis is the LENGTH of the
// serial barrier-coupled chain: 32 chunks x ~1.5-3k cy exposed round-trip each.
// v10 halves it: BK=128 -> 16 chunks, 2x covering work per prefetch (~1100 cy of
// split VALU + 48 MFMA), 2x A-prefetch distance, half the barrier events. A-regs
// 2-set ping-pong (16 VGPR, issue-early at iter top). Swizzled A planes (0-conflict
// formula re-derived). B per-wave direct from L2-hot wp (16 frags/chunk).
__global__ __launch_bounds__(256, 2) void moe_gate(const float* __restrict__ x,
                                                   const unsigned short* __restrict__ wp1,
                                                   const unsigned short* __restrict__ wp2,
                                                   float* __restrict__ out_idx,
                                                   float* __restrict__ out_w) {
    // [buf0: A1 0..8K, A2 8K..16K][buf1: A1 16K..24K, A2 24K..32K]; epil overlays
    __shared__ __align__(16) unsigned char smem[32768];
    float* epil = (float*)smem;                    // [32][132] f32 = 16.9 KB union

    const int tid  = threadIdx.x;
    const int lane = tid & 63;
    const int wv   = tid >> 6;        // expert group 0..3 (nt = wv*2 + j)
    const int col  = lane & 15;       // A: token-in-tile, B: expert-in-tile, D: col
    const int quad = lane >> 4;       // A/B: k-seg, D: row group
    const long tok0 = (long)blockIdx.x * TM;

    // A staging: thread t -> srow = t>>3 (0..31), skseg = t&7; covers k-segs
    // s in {skseg, skseg+8} (8 f32 each). 8 threads cover one 256B row-piece
    // (coalesced); the two pieces per thread are 256B apart.
    const int srow = tid >> 3, skseg = tid & 7;
    const float* xgs = x + (tok0 + srow) * (long)HDIM + skseg * 8;
    // swizzled plane-local byte offsets for the two cells:
    const int g0 = (skseg >> 2) * 2 + (srow >> 4);          // s = skseg
    const int g1 = ((skseg + 8) >> 2) * 2 + (srow >> 4);    // s = skseg+8
    const int adst0 = swz(g0 * 1024 + (skseg & 3) * 256 + (srow & 15) * 16);
    const int adst1 = swz(g1 * 1024 + (skseg & 3) * 256 + (srow & 15) * 16);

    f32x4 acc[2][2], accc[2][2];      // [m][j] main + cross (static-indexed)
#pragma unroll
    for (int m = 0; m < 2; ++m)
#pragma unroll
        for (int j = 0; j < 2; ++j) { acc[m][j] = (f32x4){0,0,0,0}; accc[m][j] = (f32x4){0,0,0,0}; }

    auto loadA = [&](int ch, ARegs& A) {   // 4 coalesced 16B loads
        const float* p = xgs + ch * BK;
        A.v[0] = *(const f32x4*)(p);
        A.v[1] = *(const f32x4*)(p + 4);
        A.v[2] = *(const f32x4*)(p + 64);  // kseg + 8 -> +64 floats
        A.v[3] = *(const f32x4*)(p + 68);
    };
    auto splitWriteA = [&](const ARegs& A, int b) {   // 16 splits -> 4 swizzled uint4 stores
        unsigned short h0[8], l0[8], h1[8], l1[8];
#pragma unroll
        for (int j = 0; j < 8; ++j) {
            _Float16 hh, ll;
            f16split(j < 4 ? A.v[0][j] : A.v[1][j - 4], hh, ll);
            union { _Float16 x; unsigned short u; } ch_, cl_;
            ch_.x = hh; cl_.x = ll;
            h0[j] = ch_.u; l0[j] = cl_.u;
            f16split(j < 4 ? A.v[2][j] : A.v[3][j - 4], hh, ll);
            ch_.x = hh; cl_.x = ll;
            h1[j] = ch_.u; l1[j] = cl_.u;
        }
        unsigned char* base = smem + b * 16384;
        *(uint4*)(base + adst0)        = *(const uint4*)h0;
        *(uint4*)(base + adst1)        = *(const uint4*)h1;
        *(uint4*)(base + 8192 + adst0) = *(const uint4*)l0;
        *(uint4*)(base + 8192 + adst1) = *(const uint4*)l1;
    };
    auto loadB = [&](int ch, BRegs& B) {   // 16 lane-contiguous 16B loads (1KB/instr, L2)
#pragma unroll
        for (int kk = 0; kk < 4; ++kk)
#pragma unroll
            for (int j = 0; j < 2; ++j) {
                const size_t o = (size_t)(ch * 4 + kk) * 4096
                               + (size_t)(wv * 2 + j) * 512 + (size_t)lane * 8;
                B.v[(kk * 2 + j) * 2 + 0] = *(const f16x8*)(wp1 + o);
                B.v[(kk * 2 + j) * 2 + 1] = *(const f16x8*)(wp2 + o);
            }
    };
    auto mfmaStep = [&](int b, const BRegs& B) {  // 16 conflict-free ds_read_b128 + 48 MFMA
        const unsigned char* base = smem + b * 16384;
#pragma unroll
        for (int kk = 0; kk < 4; ++kk) {
            f16x8 af1v[2], af2v[2];
#pragma unroll
            for (int m = 0; m < 2; ++m) {
                const int bo = swz((kk * 2 + m) * 1024 + lane * 16);
                af1v[m] = *(const f16x8*)(base + bo);
                af2v[m] = *(const f16x8*)(base + 8192 + bo);
            }
#pragma unroll
            for (int j = 0; j < 2; ++j) {
                f16x8 bf1 = B.v[(kk * 2 + j) * 2 + 0];
                f16x8 bf2 = B.v[(kk * 2 + j) * 2 + 1];
#pragma unroll
                for (int m = 0; m < 2; ++m) {
                    acc[m][j]  = __builtin_amdgcn_mfma_f32_16x16x32_f16(af1v[m], bf1, acc[m][j],  0, 0, 0);
                    accc[m][j] = __builtin_amdgcn_mfma_f32_16x16x32_f16(af1v[m], bf2, accc[m][j], 0, 0, 0);
                    accc[m][j] = __builtin_amdgcn_mfma_f32_16x16x32_f16(af2v[m], bf1, accc[m][j], 0, 0, 0);
                }
            }
        }
    };

    ARegs AP, AQ;                     // A ping-pong (even/odd chunks)
    BRegs B0, B1;                     // B ping-pong (even/odd chunks)

    // ---- prologue: buf0 <- A(0); A(1), B(0), B(1) in flight ----
    loadA(0, AP);
    loadB(0, B0);
    loadB(1, B1);
    splitWriteA(AP, 0);               // waits A(0) only (oldest in FIFO)
    loadA(1, AQ);
    LGKM0();
    __builtin_amdgcn_s_barrier();     // publish buf0

    // steady: iter handles compute ch (buf0) and ch+1 (buf1); stages ch+1, ch+2.
    // A issue-early at segment top into the just-freed set -> ~1-2 chunk distance.
    for (int ch = 0; ch < NCH - 2; ch += 2) {
        loadA(ch + 2, AP);            // issue early (AP consumed last iter)
        splitWriteA(AQ, 1);           // A(ch+1) -> buf1
        mfmaStep(0, B0);              // chunk ch
        loadB(ch + 2, B0);
        LGKM0();
        __builtin_amdgcn_s_barrier(); // publish buf1; buf0 reads done

        loadA(ch + 3, AQ);
        splitWriteA(AP, 0);           // A(ch+2) -> buf0
        mfmaStep(1, B1);              // chunk ch+1
        loadB(ch + 3, B1);
        LGKM0();
        __builtin_amdgcn_s_barrier(); // publish buf0; buf1 reads done
    }
    // tail: chunks NCH-2 (buf0), NCH-1 (buf1)
    splitWriteA(AQ, 1);               // A(NCH-1) -> buf1
    mfmaStep(0, B0);                  // chunk NCH-2
    LGKM0();
    __builtin_amdgcn_s_barrier();
    mfmaStep(1, B1);                  // chunk NCH-1
    __syncthreads();                  // all LDS reads done before epil overlay

    // ---- epilogue: logits -> LDS; D layout: token = m*16+quad*4+r, expert = (wv*2+j)*16+col
#pragma unroll
    for (int m = 0; m < 2; ++m)
#pragma unroll
        for (int j = 0; j < 2; ++j)
#pragma unroll
            for (int r = 0; r < 4; ++r)
                epil[(m * 16 + quad * 4 + r) * 132 + (wv * 2 + j) * 16 + col] =
                    acc[m][j][r] + accc[m][j][r] * INV_SPLIT_SCALE;
    __syncthreads();

    // ---- top-8 + renorm softmax: 8 tokens per wave (butterfly, verified) ----
    for (int i = 0; i < 8; ++i) {
        const int t = wv * 8 + i;
        float2 p = *(const float2*)(epil + t * 132 + 2 * lane);
        float v0 = p.x, v1 = p.y;
        const int i0 = 2 * lane, i1 = 2 * lane + 1;

        float topv[TOPK];
        int topi[TOPK];
#pragma unroll
        for (int s = 0; s < TOPK; ++s) {
            float mv = (v0 >= v1) ? v0 : v1;          // tie -> smaller index
            int   mi = (v0 >= v1) ? i0 : i1;
#pragma unroll
            for (int off = 32; off >= 1; off >>= 1) {
                float ov = __shfl_xor(mv, off);
                int   oi = __shfl_xor(mi, off);
                if (ov > mv || (ov == mv && oi < mi)) { mv = ov; mi = oi; }
            }
            topv[s] = mv; topi[s] = mi;
            if (i0 == mi) v0 = -INFINITY;
            if (i1 == mi) v1 = -INFINITY;
        }

        const float m = topv[0];
        float sum = 0.f;
#pragma unroll
        for (int s = 0; s < TOPK; ++s) sum += expf(topv[s] - m);
        const float inv = 1.f / sum;

        float myv = topv[0]; int myi = topi[0];
#pragma unroll
        for (int s = 1; s < TOPK; ++s)
            if (lane == s) { myv = topv[s]; myi = topi[s]; }

        if (lane < TOPK) {
            long tok = tok0 + t;
            out_idx[tok * TOPK + lane] = (float)myi;
            out_w[tok * TOPK + lane]   = expf(myv - m) * inv;
        }
    }
}

extern "C" void kernel_launch(void* const* d_in, const int* in_sizes, int n_in,
                              void* d_out, int out_size, void* d_ws, size_t ws_size,
                              hipStream_t stream) {
    const float* x = (const float*)d_in[0];   // [4,4096,2048] fp32
    const float* w = (const float*)d_in[1];   // [128,2048] fp32
    float* out = (float*)d_out;               // [T*8 idx][T*8 weights] flat fp32

    unsigned short* wp1 = (unsigned short*)d_ws;           // 512 KB packed hi
    unsigned short* wp2 = wp1 + (size_t)NEXP * HDIM;       // 512 KB packed lo

    pack_w<<<(64 * 8 * 64) / 256, 256, 0, stream>>>(w, wp1, wp2);
    moe_gate<<<T_TOKENS / TM, 256, 0, stream>>>(x, wp1, wp2, out, out + (size_t)T_TOKENS * TOPK);
}

// Round 10
// 227.956 us; speedup vs baseline: 1.0888x; 1.0280x over previous
//
#include <hip/hip_runtime.h>
#include <math.h>

#define T_TOKENS 16384
#define HDIM     2048
#define NEXP     128
#define TOPK     8

#define BK    128                // k per chunk (4 MFMA k-steps)
#define NCH   (HDIM / BK)        // 16 chunks
#define TM    32                 // tokens per block

#define F16_MIN_NORM    6.1035156e-05f
#define SPLIT_SCALE     4096.0f
#define INV_SPLIT_SCALE 2.44140625e-04f   // 2^-12

typedef __attribute__((ext_vector_type(8))) _Float16 f16x8;  // A/B frag: 4 VGPR
typedef __attribute__((ext_vector_type(4))) float    f32x4;  // C/D frag + loads

#define LGKM0()   asm volatile("s_waitcnt lgkmcnt(0)" ::: "memory")

// x = hi + lo*2^-12 (f16 RNE each); residual <= 2^-24|x|. Numerics verified R3-R8.
__device__ __forceinline__ void f16split(float f, _Float16& hi, _Float16& lo) {
    _Float16 h = (_Float16)f;
    float back = (float)h;
    if (fabsf(f) < F16_MIN_NORM) { h = (_Float16)0.f; back = 0.f; }
    lo = (_Float16)((f - back) * SPLIT_SCALE);
    hi = h;
}

// A-plane LDS swizzle (plane = 8192 B). Write byte = g*1024 + (skseg&3)*256 +
// (srow&15)*16, g = (skseg>>2)*2 + (srow>>4). Unswizzled write granule = srow&15
// fixed per 16-lane quarter -> 16-way. Swizzled: granule' = (srow&7) ^ (skseg&3)
// ^ (((skseg>>2)&1)<<2); skseg spans 0..15 per quarter -> 8 granules x2 = free.
// Read granule' = (lane&7) ^ ((lane>>4)&3) ^ const -> 2-way free. Bijective.
// (0 conflicts verified on HW in R8/R9 with the same formula.)
__device__ __forceinline__ int swz(int b) {
    return b ^ (((b >> 8) & 3) << 4) ^ (((b >> 11) & 1) << 6);
}

// ---- prep: split w AND repack into MFMA B-frag order (verified, unchanged) ----
// packed[s]: ((kkg*8 + nt)*64 + lane) * 8 f16; kkg = global 32-k step, nt = expert/16.
__global__ __launch_bounds__(256) void pack_w(const float* __restrict__ w,
                                              unsigned short* __restrict__ wp1,
                                              unsigned short* __restrict__ wp2) {
    int p = blockIdx.x * 256 + threadIdx.x;       // 0 .. 64*8*64-1
    int lane = p & 63, nt = (p >> 6) & 7, kk = p >> 9;
    int col = lane & 15, quad = lane >> 4;
    const float* src = w + (size_t)(nt * 16 + col) * HDIM + kk * 32 + quad * 8;
    unsigned short h[8], l[8];
#pragma unroll
    for (int j = 0; j < 8; ++j) {
        _Float16 hh, ll;
        f16split(src[j], hh, ll);
        union { _Float16 x; unsigned short u; } ch, cl;
        ch.x = hh; cl.x = ll;
        h[j] = ch.u; l[j] = cl.u;
    }
    *(uint4*)(wp1 + (size_t)p * 8) = *(const uint4*)h;
    *(uint4*)(wp2 + (size_t)p * 8) = *(const uint4*)l;
}

struct ARegs { f32x4 v[2]; };     // 8 f32 at kseg = skseg — static idx
struct BRegs { f16x8 v[8]; };     // [kk(4)][plane(2)] — static idx

// ---- fused gate v11: R9 re-divided for 16 waves/CU (the untested TLP axis) ----
// Ten rounds of evidence: every variant ran exactly 8 waves/CU (2/SIMD, minimum
// hiding) with waves ~85% stalled; ILP pipelines collapse in regalloc (5x), but
// TLP needs no compiler cooperation. v11: 512-thr blocks (8 waves, 1 n-tile each),
// grid 512 -> 2 blocks/CU x 8 waves = 4 waves/SIMD. Per-wave state halves (B 8
// frags, acc 2x1) -> VGPR <= 128 enforced by __launch_bounds__(512,4). Same TM,
// BK, traffic, swizzle, numerics as R9 — only the TLP axis varies.
__global__ __launch_bounds__(512, 4) void moe_gate(const float* __restrict__ x,
                                                   const unsigned short* __restrict__ wp1,
                                                   const unsigned short* __restrict__ wp2,
                                                   float* __restrict__ out_idx,
                                                   float* __restrict__ out_w) {
    // [buf0: A1 0..8K, A2 8K..16K][buf1: 16K..32K]; epil overlays
    __shared__ __align__(16) unsigned char smem[32768];
    float* epil = (float*)smem;                    // [32][132] f32 = 16.9 KB union

    const int tid  = threadIdx.x;
    const int lane = tid & 63;
    const int wv   = tid >> 6;        // 0..7; owns n-tile nt = wv (16 experts)
    const int col  = lane & 15;       // A: token-in-tile, B: expert-in-tile, D: col
    const int quad = lane >> 4;       // A/B: k-seg, D: row group
    const long tok0 = (long)blockIdx.x * TM;

    // A staging: thread t -> srow = t>>4 (0..31), skseg = t&15 -> 8 f32 at k=skseg*8.
    // 16 threads cover one 512B row-piece (coalesced).
    const int srow = tid >> 4, skseg = tid & 15;
    const float* xgs = x + (tok0 + srow) * (long)HDIM + skseg * 8;
    const int g0 = (skseg >> 2) * 2 + (srow >> 4);
    const int adst = swz(g0 * 1024 + (skseg & 3) * 256 + (srow & 15) * 16);

    f32x4 acc[2], accc[2];            // [m] main + cross (static-indexed)
#pragma unroll
    for (int m = 0; m < 2; ++m) { acc[m] = (f32x4){0,0,0,0}; accc[m] = (f32x4){0,0,0,0}; }

    auto loadA = [&](int ch, ARegs& A) {   // 2 coalesced 16B loads
        const float* p = xgs + ch * BK;
        A.v[0] = *(const f32x4*)(p);
        A.v[1] = *(const f32x4*)(p + 4);
    };
    auto splitWriteA = [&](const ARegs& A, int b) {   // 8 splits -> 2 swizzled uint4 stores
        unsigned short h[8], l[8];
#pragma unroll
        for (int j = 0; j < 8; ++j) {
            _Float16 hh, ll;
            f16split(j < 4 ? A.v[0][j] : A.v[1][j - 4], hh, ll);
            union { _Float16 x; unsigned short u; } ch_, cl_;
            ch_.x = hh; cl_.x = ll;
            h[j] = ch_.u; l[j] = cl_.u;
        }
        unsigned char* base = smem + b * 16384;
        *(uint4*)(base + adst)        = *(const uint4*)h;
        *(uint4*)(base + 8192 + adst) = *(const uint4*)l;
    };
    auto loadB = [&](int ch, BRegs& B) {   // 8 lane-contiguous 16B loads (1KB/instr, L2)
#pragma unroll
        for (int kk = 0; kk < 4; ++kk) {
            const size_t o = (size_t)(ch * 4 + kk) * 4096 + (size_t)wv * 512 + (size_t)lane * 8;
            B.v[kk * 2 + 0] = *(const f16x8*)(wp1 + o);
            B.v[kk * 2 + 1] = *(const f16x8*)(wp2 + o);
        }
    };
    auto mfmaStep = [&](int b, const BRegs& B) {  // 8 conflict-free ds_read_b128 + 24 MFMA
        const unsigned char* base = smem + b * 16384;
#pragma unroll
        for (int kk = 0; kk < 4; ++kk) {
            f16x8 af1v[2], af2v[2];
#pragma unroll
            for (int m = 0; m < 2; ++m) {
                const int bo = swz((kk * 2 + m) * 1024 + lane * 16);
                af1v[m] = *(const f16x8*)(base + bo);
                af2v[m] = *(const f16x8*)(base + 8192 + bo);
            }
            f16x8 bf1 = B.v[kk * 2 + 0];
            f16x8 bf2 = B.v[kk * 2 + 1];
#pragma unroll
            for (int m = 0; m < 2; ++m) {
                acc[m]  = __builtin_amdgcn_mfma_f32_16x16x32_f16(af1v[m], bf1, acc[m],  0, 0, 0);
                accc[m] = __builtin_amdgcn_mfma_f32_16x16x32_f16(af1v[m], bf2, accc[m], 0, 0, 0);
                accc[m] = __builtin_amdgcn_mfma_f32_16x16x32_f16(af2v[m], bf1, accc[m], 0, 0, 0);
            }
        }
    };

    ARegs AP, AQ;                     // A ping-pong (even/odd chunks)
    BRegs B0, B1;                     // B ping-pong (even/odd chunks)

    // ---- prologue: buf0 <- A(0); A(1), B(0), B(1) in flight ----
    loadA(0, AP);
    loadB(0, B0);
    loadB(1, B1);
    splitWriteA(AP, 0);               // waits A(0) only (oldest in FIFO)
    loadA(1, AQ);
    LGKM0();
    __builtin_amdgcn_s_barrier();     // publish buf0

    for (int ch = 0; ch < NCH - 2; ch += 2) {
        loadA(ch + 2, AP);            // issue early (AP consumed last iter)
        splitWriteA(AQ, 1);           // A(ch+1) -> buf1
        mfmaStep(0, B0);              // chunk ch
        loadB(ch + 2, B0);
        LGKM0();
        __builtin_amdgcn_s_barrier(); // publish buf1; buf0 reads done

        loadA(ch + 3, AQ);
        splitWriteA(AP, 0);           // A(ch+2) -> buf0
        mfmaStep(1, B1);              // chunk ch+1
        loadB(ch + 3, B1);
        LGKM0();
        __builtin_amdgcn_s_barrier(); // publish buf0; buf1 reads done
    }
    // tail: chunks NCH-2 (buf0), NCH-1 (buf1)
    splitWriteA(AQ, 1);               // A(NCH-1) -> buf1
    mfmaStep(0, B0);                  // chunk NCH-2
    LGKM0();
    __builtin_amdgcn_s_barrier();
    mfmaStep(1, B1);                  // chunk NCH-1
    __syncthreads();                  // all LDS reads done before epil overlay

    // ---- epilogue: logits -> LDS; D layout: token = m*16+quad*4+r, expert = wv*16+col
#pragma unroll
    for (int m = 0; m < 2; ++m)
#pragma unroll
        for (int r = 0; r < 4; ++r)
            epil[(m * 16 + quad * 4 + r) * 132 + wv * 16 + col] =
                acc[m][r] + accc[m][r] * INV_SPLIT_SCALE;
    __syncthreads();

    // ---- top-8 + renorm softmax: 4 tokens per wave (butterfly, verified) ----
    for (int i = 0; i < 4; ++i) {
        const int t = wv * 4 + i;
        float2 p = *(const float2*)(epil + t * 132 + 2 * lane);
        float v0 = p.x, v1 = p.y;
        const int i0 = 2 * lane, i1 = 2 * lane + 1;

        float topv[TOPK];
        int topi[TOPK];
#pragma unroll
        for (int s = 0; s < TOPK; ++s) {
            float mv = (v0 >= v1) ? v0 : v1;          // tie -> smaller index
            int   mi = (v0 >= v1) ? i0 : i1;
#pragma unroll
            for (int off = 32; off >= 1; off >>= 1) {
                float ov = __shfl_xor(mv, off);
                int   oi = __shfl_xor(mi, off);
                if (ov > mv || (ov == mv && oi < mi)) { mv = ov; mi = oi; }
            }
            topv[s] = mv; topi[s] = mi;
            if (i0 == mi) v0 = -INFINITY;
            if (i1 == mi) v1 = -INFINITY;
        }

        const float m = topv[0];
        float sum = 0.f;
#pragma unroll
        for (int s = 0; s < TOPK; ++s) sum += expf(topv[s] - m);
        const float inv = 1.f / sum;

        float myv = topv[0]; int myi = topi[0];
#pragma unroll
        for (int s = 1; s < TOPK; ++s)
            if (lane == s) { myv = topv[s]; myi = topi[s]; }

        if (lane < TOPK) {
            long tok = tok0 + t;
            out_idx[tok * TOPK + lane] = (float)myi;
            out_w[tok * TOPK + lane]   = expf(myv - m) * inv;
        }
    }
}

extern "C" void kernel_launch(void* const* d_in, const int* in_sizes, int n_in,
                              void* d_out, int out_size, void* d_ws, size_t ws_size,
                              hipStream_t stream) {
    const float* x = (const float*)d_in[0];   // [4,4096,2048] fp32
    const float* w = (const float*)d_in[1];   // [128,2048] fp32
    float* out = (float*)d_out;               // [T*8 idx][T*8 weights] flat fp32

    unsigned short* wp1 = (unsigned short*)d_ws;           // 512 KB packed hi
    unsigned short* wp2 = wp1 + (size_t)NEXP * HDIM;       // 512 KB packed lo

    pack_w<<<(64 * 8 * 64) / 256, 256, 0, stream>>>(w, wp1, wp2);
    moe_gate<<<T_TOKENS / TM, 512, 0, stream>>>(x, wp1, wp2, out, out + (size_t)T_TOKENS * TOPK);
}